// Round 4
// baseline (389.206 us; speedup 1.0000x reference)
//
#include <hip/hip_runtime.h>
#include <hip/hip_bf16.h>
#include <type_traits>

#define FEAT 128

typedef unsigned int uint32;
typedef unsigned short ushort16;
typedef __attribute__((ext_vector_type(8))) short short8;
typedef __attribute__((ext_vector_type(4))) float v4f;

// ---- bf16 helpers (RNE round; bf16->f32 is exact shift) ---------------------
__device__ __forceinline__ ushort16 f2bf(float f) {
    uint32 u = __float_as_uint(f);
    u += 0x7fffu + ((u >> 16) & 1u);
    return (ushort16)(u >> 16);
}
__device__ __forceinline__ float bflo(uint32 u) { return __uint_as_float(u << 16); }
__device__ __forceinline__ float bfhi(uint32 u) { return __uint_as_float(u & 0xffff0000u); }

// ---------------- histogram of col (in-degree, without self-loop) ------------
__global__ void hist_kernel(const int* __restrict__ col, int* __restrict__ counts, int E) {
    int e = blockIdx.x * 256 + threadIdx.x;
    if (e < E) atomicAdd(&counts[col[e]], 1);
}

// ---------------- scan step 1: per-1024-chunk sums ---------------------------
__global__ __launch_bounds__(256) void scan_part(const int* __restrict__ counts,
                                                 int* __restrict__ bsum, int n) {
    __shared__ int s[256];
    int base = blockIdx.x * 1024;
    int t = threadIdx.x;
    int v = 0;
#pragma unroll
    for (int i = 0; i < 4; i++) {
        int idx = base + t * 4 + i;
        if (idx < n) v += counts[idx];
    }
    s[t] = v;
    __syncthreads();
    for (int o = 128; o > 0; o >>= 1) {
        if (t < o) s[t] += s[t + o];
        __syncthreads();
    }
    if (t == 0) bsum[blockIdx.x] = s[0];
}

// ---------------- scan step 2: exclusive scan of block sums (nb <= 128) ------
__global__ void scan_bsum(int* __restrict__ bsum, int nb) {
    __shared__ int s[128];
    int t = threadIdx.x;
    int v0 = (t < nb) ? bsum[t] : 0;
    s[t] = v0;
    __syncthreads();
    for (int o = 1; o < 128; o <<= 1) {
        int v = (t >= o) ? s[t - o] : 0;
        __syncthreads();
        s[t] += v;
        __syncthreads();
    }
    if (t < nb) bsum[t] = s[t] - v0;  // exclusive
}

// ---------------- scan step 3: final offsets + next[] + dinv -----------------
__global__ __launch_bounds__(256) void scan_final(const int* __restrict__ counts,
                                                  const int* __restrict__ bsum,
                                                  int* __restrict__ off, int* __restrict__ nxt,
                                                  float* __restrict__ dinv, int n) {
    __shared__ int s[256];
    int base = blockIdx.x * 1024;
    int t = threadIdx.x;
    int c[4];
    int sum = 0;
#pragma unroll
    for (int i = 0; i < 4; i++) {
        int idx = base + t * 4 + i;
        c[i] = (idx < n) ? counts[idx] : 0;
        sum += c[i];
    }
    int v0 = sum;
    s[t] = sum;
    __syncthreads();
    for (int o = 1; o < 256; o <<= 1) {
        int v = (t >= o) ? s[t - o] : 0;
        __syncthreads();
        s[t] += v;
        __syncthreads();
    }
    int excl = s[t] - v0 + bsum[blockIdx.x];
#pragma unroll
    for (int i = 0; i < 4; i++) {
        int idx = base + t * 4 + i;
        if (idx < n) {
            off[idx] = excl;
            nxt[idx] = excl;
            dinv[idx] = rsqrtf((float)(c[i] + 1));  // +1 = self loop
        }
        excl += c[i];
    }
    if (blockIdx.x == gridDim.x - 1 && t == 255) off[n] = excl;  // == E
}

// ---------------- CSR fill: edge record (src, dinv[src]) packed as uint2 -----
__global__ void fill_kernel(const int* __restrict__ row, const int* __restrict__ col,
                            const float* __restrict__ dinv, int* __restrict__ nxt,
                            uint2* __restrict__ erec, int E) {
    int e = blockIdx.x * 256 + threadIdx.x;
    if (e < E) {
        int c = col[e], r = row[e];
        int p = atomicAdd(&nxt[c], 1);
        erec[p] = make_uint2((uint32)r, __float_as_uint(dinv[r]));
    }
}

// ---------------- convert W0/1/2 (fp32, row-major [k][n]) -> bf16 transposed [n][k]
__global__ __launch_bounds__(256) void cvt_w_kernel(const float* __restrict__ W0,
                                                    const float* __restrict__ W1,
                                                    const float* __restrict__ W2,
                                                    ushort16* __restrict__ Wt) {
    int id = blockIdx.x * 256 + threadIdx.x;
    if (id >= 3 * 16384) return;
    int m = id >> 14;
    int o = id & 16383;
    int ncol = o >> 7;   // output row  (= W column)
    int k = o & 127;     // output col  (= W row)
    const float* W = (m == 0) ? W0 : (m == 1) ? W1 : W2;
    Wt[id] = f2bf(W[(size_t)k * FEAT + ncol]);
}

// ---------------- bf16 MFMA GEMM: Ch = bf16(A @ W), W given transposed -------
// Persistent: 512 blocks stage Wt once, hold all B-fragments in registers
// (no LDS in the main loop). OPERAND SWAP: mfma(Wfrag, Afrag) makes the D
// n-dim (col=lane&15) the node row and the m-dim (quad*4+reg) the W column,
// so each lane holds 4 consecutive output columns of one row -> direct 8B
// packed bf16 stores, no LDS repack epilogue.
template <typename T>
__global__ __launch_bounds__(256, 2) void gemm_mfma(const T* __restrict__ A,
                                                    const ushort16* __restrict__ Wt,
                                                    ushort16* __restrict__ Ch, int n) {
    __shared__ ushort16 sW[128 * 136];  // stride 136: 2-way bank alias = free

    const int t = threadIdx.x;
    {
        int r = t >> 1, half = t & 1;
        const ushort16* s = Wt + (size_t)r * 128 + half * 64;
        ushort16* d = sW + r * 136 + half * 64;
#pragma unroll
        for (int i = 0; i < 8; i++)
            *(uint4*)(d + i * 8) = *(const uint4*)(s + i * 8);
    }
    __syncthreads();

    const int w = t >> 6;
    const int lane = t & 63;
    const int quad = lane >> 4;
    const int l16 = lane & 15;

    // W-fragments (MFMA A-operand): m = l16 = W column (Wt row), k = quad*8+ks*32+j
    short8 bw[8][4];
#pragma unroll
    for (int ct = 0; ct < 8; ct++) {
        const ushort16* bp = sW + (ct * 16 + l16) * 136 + quad * 8;
#pragma unroll
        for (int ks = 0; ks < 4; ks++) bw[ct][ks] = *(const short8*)(bp + ks * 32);
    }

    const int nTiles = (n + 15) >> 4;
    for (int tile = blockIdx.x * 4 + w; tile < nTiles; tile += gridDim.x * 4) {
        const int row = tile * 16 + l16;  // node row (MFMA B-operand n-index)
        short8 a[4];
        if (row < n) {
            if constexpr (std::is_same<T, float>::value) {
#pragma unroll
                for (int ks = 0; ks < 4; ks++) {
                    const float* ap = A + (size_t)row * FEAT + quad * 8 + ks * 32;
                    float4 f0 = *(const float4*)ap;
                    float4 f1 = *(const float4*)(ap + 4);
                    short8 v;
                    v[0] = f2bf(f0.x); v[1] = f2bf(f0.y); v[2] = f2bf(f0.z); v[3] = f2bf(f0.w);
                    v[4] = f2bf(f1.x); v[5] = f2bf(f1.y); v[6] = f2bf(f1.z); v[7] = f2bf(f1.w);
                    a[ks] = v;
                }
            } else {
                const ushort16* ap = A + (size_t)row * FEAT + quad * 8;
#pragma unroll
                for (int ks = 0; ks < 4; ks++) a[ks] = *(const short8*)(ap + ks * 32);
            }
        } else {
#pragma unroll
            for (int ks = 0; ks < 4; ks++) a[ks] = (short8)0;
        }

        v4f acc[8];
#pragma unroll
        for (int ct = 0; ct < 8; ct++) acc[ct] = (v4f)0.f;
#pragma unroll
        for (int ct = 0; ct < 8; ct++)
#pragma unroll
            for (int ks = 0; ks < 4; ks++)
                acc[ct] = __builtin_amdgcn_mfma_f32_16x16x32_bf16(bw[ct][ks], a[ks], acc[ct], 0, 0, 0);

        if (row < n) {
#pragma unroll
            for (int ct = 0; ct < 8; ct++) {
                uint2 o;
                o.x = (uint32)f2bf(acc[ct][0]) | ((uint32)f2bf(acc[ct][1]) << 16);
                o.y = (uint32)f2bf(acc[ct][2]) | ((uint32)f2bf(acc[ct][3]) << 16);
                *(uint2*)(Ch + (size_t)row * FEAT + ct * 16 + quad * 4) = o;
            }
        }
    }
}

// ---------------- gather-propagate over bf16 table ---------------------------
// H[c] = dinv[c]^2*XW[c] + sum_e dinv[c]*dinv[src_e]*XW[src_e]
// 8 edge-groups x 8 lanes (up to 8 edges in flight/wave ~= avg degree);
// each lane covers 32B of the row (2 x uint4); 3-step butterfly combine.
// mode 0: write bf16; mode 1: leaky_relu(0.01) then bf16; mode 2: write fp32
__global__ __launch_bounds__(256) void gather_kernel(const int* __restrict__ off,
                                                     const uint2* __restrict__ erec,
                                                     const float* __restrict__ dinv,
                                                     const ushort16* __restrict__ XWh,
                                                     ushort16* __restrict__ Hh,
                                                     float* __restrict__ Hf,
                                                     int n, int mode) {
    int node = blockIdx.x * 4 + (threadIdx.x >> 6);
    if (node >= n) return;
    int lane = threadIdx.x & 63;
    int grp = lane >> 3;  // edge group 0..7
    int l8 = lane & 7;    // 32B chunk within row
    float dc = dinv[node];
    const uint4* table = (const uint4*)XWh;  // row = 16 x uint4

    float acc[16];
    if (grp == 0) {  // self-loop term
        size_t b = (size_t)node * 16 + l8 * 2;
        uint4 v0 = table[b], v1 = table[b + 1];
        float w0 = dc * dc;
        acc[0] = w0 * bflo(v0.x); acc[1] = w0 * bfhi(v0.x);
        acc[2] = w0 * bflo(v0.y); acc[3] = w0 * bfhi(v0.y);
        acc[4] = w0 * bflo(v0.z); acc[5] = w0 * bfhi(v0.z);
        acc[6] = w0 * bflo(v0.w); acc[7] = w0 * bfhi(v0.w);
        acc[8] = w0 * bflo(v1.x); acc[9] = w0 * bfhi(v1.x);
        acc[10] = w0 * bflo(v1.y); acc[11] = w0 * bfhi(v1.y);
        acc[12] = w0 * bflo(v1.z); acc[13] = w0 * bfhi(v1.z);
        acc[14] = w0 * bflo(v1.w); acc[15] = w0 * bfhi(v1.w);
    } else {
#pragma unroll
        for (int j = 0; j < 16; j++) acc[j] = 0.f;
    }

    int s = off[node], e = off[node + 1];
    for (int i = s + grp; i < e; i += 8) {
        uint2 er = erec[i];
        float nrm = dc * __uint_as_float(er.y);
        size_t rb = (size_t)er.x * 16 + l8 * 2;
        uint4 u0 = table[rb], u1 = table[rb + 1];
        acc[0] += nrm * bflo(u0.x); acc[1] += nrm * bfhi(u0.x);
        acc[2] += nrm * bflo(u0.y); acc[3] += nrm * bfhi(u0.y);
        acc[4] += nrm * bflo(u0.z); acc[5] += nrm * bfhi(u0.z);
        acc[6] += nrm * bflo(u0.w); acc[7] += nrm * bfhi(u0.w);
        acc[8] += nrm * bflo(u1.x); acc[9] += nrm * bfhi(u1.x);
        acc[10] += nrm * bflo(u1.y); acc[11] += nrm * bfhi(u1.y);
        acc[12] += nrm * bflo(u1.z); acc[13] += nrm * bfhi(u1.z);
        acc[14] += nrm * bflo(u1.w); acc[15] += nrm * bfhi(u1.w);
    }

    // combine the 8 groups (lane bits 3,4,5); all lanes end with full sums
#pragma unroll
    for (int j = 0; j < 16; j++) {
        acc[j] += __shfl_xor(acc[j], 8);
        acc[j] += __shfl_xor(acc[j], 16);
        acc[j] += __shfl_xor(acc[j], 32);
    }

    if (mode == 2) {
        float* hp = Hf + (size_t)node * FEAT + l8 * 16;
        if (grp == 0) {
            *(float4*)(hp + 0) = make_float4(acc[0], acc[1], acc[2], acc[3]);
            *(float4*)(hp + 4) = make_float4(acc[4], acc[5], acc[6], acc[7]);
        } else if (grp == 1) {
            *(float4*)(hp + 8) = make_float4(acc[8], acc[9], acc[10], acc[11]);
            *(float4*)(hp + 12) = make_float4(acc[12], acc[13], acc[14], acc[15]);
        }
    } else {
        if (mode == 1) {
#pragma unroll
            for (int j = 0; j < 16; j++) acc[j] = (acc[j] >= 0.f) ? acc[j] : 0.01f * acc[j];
        }
        if (grp == 0) {
            uint4 o0, o1;
            o0.x = (uint32)f2bf(acc[0]) | ((uint32)f2bf(acc[1]) << 16);
            o0.y = (uint32)f2bf(acc[2]) | ((uint32)f2bf(acc[3]) << 16);
            o0.z = (uint32)f2bf(acc[4]) | ((uint32)f2bf(acc[5]) << 16);
            o0.w = (uint32)f2bf(acc[6]) | ((uint32)f2bf(acc[7]) << 16);
            o1.x = (uint32)f2bf(acc[8]) | ((uint32)f2bf(acc[9]) << 16);
            o1.y = (uint32)f2bf(acc[10]) | ((uint32)f2bf(acc[11]) << 16);
            o1.z = (uint32)f2bf(acc[12]) | ((uint32)f2bf(acc[13]) << 16);
            o1.w = (uint32)f2bf(acc[14]) | ((uint32)f2bf(acc[15]) << 16);
            ushort16* hp = Hh + (size_t)node * FEAT + l8 * 16;
            *(uint4*)(hp + 0) = o0;
            *(uint4*)(hp + 8) = o1;
        }
    }
}

// ---------------- pooling: out[batch[i]] += H[i]; batch sorted ---------------
__global__ __launch_bounds__(128) void pool_kernel(const float* __restrict__ H,
                                                   const int* __restrict__ batch,
                                                   float* __restrict__ out, int n) {
    int t = threadIdx.x;  // feature
    int i0 = blockIdx.x * 64;
    if (i0 >= n) return;
    int i1 = min(i0 + 64, n);
    float acc = 0.f;
    int g = batch[i0];
    for (int i = i0; i < i1; i++) {
        int b = batch[i];
        if (b != g) {
            atomicAdd(&out[(size_t)g * FEAT + t], acc);
            acc = 0.f;
            g = b;
        }
        acc += H[(size_t)i * FEAT + t];
    }
    atomicAdd(&out[(size_t)g * FEAT + t], acc);
}

extern "C" void kernel_launch(void* const* d_in, const int* in_sizes, int n_in,
                              void* d_out, int out_size, void* d_ws, size_t ws_size,
                              hipStream_t stream) {
    const float* x = (const float*)d_in[0];
    const int* ei = (const int*)d_in[1];
    const int* batch = (const int*)d_in[2];
    const float* W0 = (const float*)d_in[3];
    const float* W1 = (const float*)d_in[4];
    const float* W2 = (const float*)d_in[5];
    float* out = (float*)d_out;

    const int N = in_sizes[0] / FEAT;  // 100000
    const int E = in_sizes[1] / 2;     // 640000

    const int* rowI = ei;
    const int* colI = ei + E;

    char* ws = (char*)d_ws;
    auto take = [&](size_t bytes) {
        char* p = ws;
        ws += (bytes + 15) & ~(size_t)15;
        return p;
    };
    int* counts   = (int*)take((size_t)N * 4);
    int* off      = (int*)take((size_t)(N + 1) * 4);
    int* nxt      = (int*)take((size_t)N * 4);
    float* dinv   = (float*)take((size_t)N * 4);
    int* bsum     = (int*)take(128 * 4);
    uint2* erec   = (uint2*)take((size_t)E * 8);
    ushort16* Wt  = (ushort16*)take((size_t)3 * 16384 * 2);
    ushort16* Hh  = (ushort16*)take((size_t)N * FEAT * 2);
    ushort16* XWh = (ushort16*)take((size_t)N * FEAT * 2);
    float* Hf     = (float*)take((size_t)N * FEAT * 4);

    const int nb = (N + 1023) / 1024;
    const int eb = (E + 255) / 256;

    // ---- weights -> bf16 transposed ----
    cvt_w_kernel<<<(3 * 16384 + 255) / 256, 256, 0, stream>>>(W0, W1, W2, Wt);

    // ---- degree + CSR build ----
    hipMemsetAsync(counts, 0, (size_t)N * 4, stream);
    hist_kernel<<<eb, 256, 0, stream>>>(colI, counts, E);
    scan_part<<<nb, 256, 0, stream>>>(counts, bsum, N);
    scan_bsum<<<1, 128, 0, stream>>>(bsum, nb);
    scan_final<<<nb, 256, 0, stream>>>(counts, bsum, off, nxt, dinv, N);
    fill_kernel<<<eb, 256, 0, stream>>>(rowI, colI, dinv, nxt, erec, E);

    const int gemmBlocks = 512;  // persistent-ish; each block stages Wt once
    const int gatBlocks = (N + 3) / 4;

    // ---- layer 0 (x fp32 -> bf16 fused in GEMM) ----
    gemm_mfma<float><<<gemmBlocks, 256, 0, stream>>>(x, Wt, XWh, N);
    gather_kernel<<<gatBlocks, 256, 0, stream>>>(off, erec, dinv, XWh, Hh, nullptr, N, 0);
    // ---- layer 1 (+leaky on output) ----
    gemm_mfma<ushort16><<<gemmBlocks, 256, 0, stream>>>(Hh, Wt + 16384, XWh, N);
    gather_kernel<<<gatBlocks, 256, 0, stream>>>(off, erec, dinv, XWh, Hh, nullptr, N, 1);
    // ---- layer 2 (fp32 output for pooling precision) ----
    gemm_mfma<ushort16><<<gemmBlocks, 256, 0, stream>>>(Hh, Wt + 2 * 16384, XWh, N);
    gather_kernel<<<gatBlocks, 256, 0, stream>>>(off, erec, dinv, XWh, nullptr, Hf, N, 2);

    // ---- global_add_pool ----
    hipMemsetAsync(out, 0, (size_t)out_size * 4, stream);
    pool_kernel<<<(N + 63) / 64, 128, 0, stream>>>(Hf, batch, out, N);
}